// Round 1
// baseline (598.790 us; speedup 1.0000x reference)
//
#include <hip/hip_runtime.h>
#include <math.h>

// ---------------------------------------------------------------------------
// TransferSH: per-point deg-3 SH evaluation + tiny per-frame affine MLP.
//
// Inputs (setup_inputs order):
//   0 positions  (N,3)  f32
//   1 indexes    (N,)   i32
//   2 cam_pos    (3,)   f32
//   3 glo_feature(1,16) f32
//   4 base_sh    (P,3,1) f32
//   5 higher_sh  (P,3,15) f32
//   6 w1 (16,32)  7 b1 (32)  8 ln_w (32)  9 ln_b (32)  10 w2 (32,12)  11 b2 (12)
// Output: [clip(out,0,1) (N,3) ; mean(|affine_res|) scalar]  -> out_size = 3N+1
// ---------------------------------------------------------------------------

// --- prologue: the whole MLP is ~900 FLOPs on a (1,16) vector; run it once
// on a single thread, write affine (3x4, +eye) to d_ws and the scalar output.
__global__ void mlp_prologue_kernel(const float* __restrict__ glo,
                                    const float* __restrict__ w1,
                                    const float* __restrict__ b1,
                                    const float* __restrict__ ln_w,
                                    const float* __restrict__ ln_b,
                                    const float* __restrict__ w2,
                                    const float* __restrict__ b2,
                                    float* __restrict__ affine_out, // 12 f32 in ws
                                    float* __restrict__ mean_out)   // d_out tail
{
    float h[32];
    #pragma unroll
    for (int j = 0; j < 32; ++j) {
        float s = b1[j];
        #pragma unroll
        for (int k = 0; k < 16; ++k) s += glo[k] * w1[k * 32 + j];
        h[j] = s;
    }
    float mu = 0.f;
    #pragma unroll
    for (int j = 0; j < 32; ++j) mu += h[j];
    mu *= (1.f / 32.f);
    float var = 0.f;
    #pragma unroll
    for (int j = 0; j < 32; ++j) { float d = h[j] - mu; var += d * d; }
    var *= (1.f / 32.f);
    float inv = rsqrtf(var + 1e-5f);
    #pragma unroll
    for (int j = 0; j < 32; ++j) {
        float v = (h[j] - mu) * inv * ln_w[j] + ln_b[j];
        h[j] = v > 0.f ? v : 0.f;
    }
    float sabs = 0.f;
    #pragma unroll
    for (int i = 0; i < 12; ++i) {
        float s = b2[i];
        #pragma unroll
        for (int j = 0; j < 32; ++j) s += h[j] * w2[j * 12 + i];
        s *= 1e-12f;                       // affine_res element
        sabs += fabsf(s);
        // affine = affine_res + eye(3,4): flat diag at 0,5,10
        float e = ((i & 3) == (i >> 2)) ? 1.f : 0.f;
        affine_out[i] = s + e;
    }
    *mean_out = sabs * (1.f / 12.f);
}

__global__ __launch_bounds__(256) void transfer_sh_kernel(
    const float* __restrict__ positions,
    const int*   __restrict__ indexes,
    const float* __restrict__ cam_pos,
    const float* __restrict__ base_sh,
    const float* __restrict__ higher_sh,
    const float* __restrict__ affine,   // 12 f32 (row-major 3x4), from ws
    float* __restrict__ out,            // (N,3)
    int n)
{
    int i = blockIdx.x * blockDim.x + threadIdx.x;
    if (i >= n) return;

    // direction
    float px = positions[3 * i + 0] - cam_pos[0];
    float py = positions[3 * i + 1] - cam_pos[1];
    float pz = positions[3 * i + 2] - cam_pos[2];
    float rn = rsqrtf(px * px + py * py + pz * pz);
    float x = px * rn, y = py * rn, z = pz * rn;

    float xx = x * x, yy = y * y, zz = z * z;
    float xy = x * y, yz = y * z, xz = x * z;

    // deg-3 SH basis (16 terms)
    float b[16];
    b[0]  = 0.28209479177387814f;
    b[1]  = -0.4886025119029199f * y;
    b[2]  =  0.4886025119029199f * z;
    b[3]  = -0.4886025119029199f * x;
    b[4]  =  1.0925484305920792f * xy;
    b[5]  = -1.0925484305920792f * yz;
    b[6]  =  0.31539156525252005f * (2.f * zz - xx - yy);
    b[7]  = -1.0925484305920792f * xz;
    b[8]  =  0.5462742152960396f * (xx - yy);
    b[9]  = -0.5900435899266435f * y * (3.f * xx - yy);
    b[10] =  2.890611442640554f  * xy * z;
    b[11] = -0.4570457994644658f * y * (4.f * zz - xx - yy);
    b[12] =  0.3731763325901154f * z * (2.f * zz - 3.f * xx - 3.f * yy);
    b[13] = -0.4570457994644658f * x * (4.f * zz - xx - yy);
    b[14] =  1.445305721320277f  * z * (xx - yy);
    b[15] = -0.5900435899266435f * x * (xx - yy);

    // gather SH coefficients
    long idx = (long)indexes[i];
    const float* bs = base_sh + 3 * idx;           // 3 contiguous floats
    const float* hs = higher_sh + 45 * idx;        // 45 contiguous floats

    float c[3];
    #pragma unroll
    for (int ch = 0; ch < 3; ++ch) {
        float s = bs[ch] * b[0];
        #pragma unroll
        for (int k = 0; k < 15; ++k) s += hs[ch * 15 + k] * b[k + 1];
        c[ch] = s + 0.5f;
    }

    // affine (broadcast load, L1/L2 resident) + clamp + store
    #pragma unroll
    for (int r = 0; r < 3; ++r) {
        float v = c[0] * affine[4 * r + 0] + c[1] * affine[4 * r + 1] +
                  c[2] * affine[4 * r + 2] + affine[4 * r + 3];
        v = fminf(fmaxf(v, 0.f), 1.f);
        out[3 * i + r] = v;
    }
}

extern "C" void kernel_launch(void* const* d_in, const int* in_sizes, int n_in,
                              void* d_out, int out_size, void* d_ws, size_t ws_size,
                              hipStream_t stream) {
    const float* positions = (const float*)d_in[0];
    const int*   indexes   = (const int*)d_in[1];
    const float* cam_pos   = (const float*)d_in[2];
    const float* glo       = (const float*)d_in[3];
    const float* base_sh   = (const float*)d_in[4];
    const float* higher_sh = (const float*)d_in[5];
    const float* w1        = (const float*)d_in[6];
    const float* b1        = (const float*)d_in[7];
    const float* ln_w      = (const float*)d_in[8];
    const float* ln_b      = (const float*)d_in[9];
    const float* w2        = (const float*)d_in[10];
    const float* b2        = (const float*)d_in[11];

    float* out    = (float*)d_out;
    float* affine = (float*)d_ws;            // 12 floats scratch

    int n = in_sizes[0] / 3;                 // number of points
    float* mean_out = out + (out_size - 1);  // scalar output at tail

    mlp_prologue_kernel<<<1, 1, 0, stream>>>(glo, w1, b1, ln_w, ln_b, w2, b2,
                                             affine, mean_out);

    int block = 256;
    int grid = (n + block - 1) / block;
    transfer_sh_kernel<<<grid, block, 0, stream>>>(positions, indexes, cam_pos,
                                                   base_sh, higher_sh, affine,
                                                   out, n);
}

// Round 2
// 578.595 us; speedup vs baseline: 1.0349x; 1.0349x over previous
//
#include <hip/hip_runtime.h>
#include <math.h>

// ---------------------------------------------------------------------------
// TransferSH: per-point deg-3 SH evaluation + tiny per-frame affine MLP.
// Inputs: 0 positions (N,3) f32, 1 indexes (N,) i32, 2 cam_pos (3,), 3 glo (1,16),
//         4 base_sh (P,3,1), 5 higher_sh (P,3,15), 6 w1(16,32), 7 b1(32),
//         8 ln_w(32), 9 ln_b(32), 10 w2(32,12), 11 b2(12)
// Output: [clip(out,0,1) (N,3) ; mean(|affine_res|)] -> out_size = 3N+1
// ---------------------------------------------------------------------------

// MLP on a (1,16) vector: one wave. Lanes 0-31 each own one hidden unit,
// wave-shuffle reduction for LayerNorm stats, lanes 0-11 produce outputs.
__global__ __launch_bounds__(64) void mlp_prologue_kernel(
    const float* __restrict__ glo,
    const float* __restrict__ w1,
    const float* __restrict__ b1,
    const float* __restrict__ ln_w,
    const float* __restrict__ ln_b,
    const float* __restrict__ w2,
    const float* __restrict__ b2,
    float* __restrict__ affine_out,  // 12 f32 in ws
    float* __restrict__ mean_out)    // d_out tail
{
    __shared__ float hsh[32];
    __shared__ float ssh[12];
    int t = threadIdx.x;

    float h = 0.f;
    if (t < 32) {
        h = b1[t];
        #pragma unroll
        for (int k = 0; k < 16; ++k) h += glo[k] * w1[k * 32 + t];
    }
    // sum over all 64 lanes (lanes >= 32 hold 0)
    float s = h;
    #pragma unroll
    for (int off = 32; off > 0; off >>= 1) s += __shfl_down(s, off);
    float mu = __shfl(s, 0) * (1.f / 32.f);

    float d = (t < 32) ? (h - mu) : 0.f;
    float v2 = d * d;
    #pragma unroll
    for (int off = 32; off > 0; off >>= 1) v2 += __shfl_down(v2, off);
    float var = __shfl(v2, 0) * (1.f / 32.f);
    float inv = rsqrtf(var + 1e-5f);

    if (t < 32) {
        float v = (h - mu) * inv * ln_w[t] + ln_b[t];
        hsh[t] = v > 0.f ? v : 0.f;
    }
    __syncthreads();
    if (t < 12) {
        float s2 = b2[t];
        #pragma unroll
        for (int j = 0; j < 32; ++j) s2 += hsh[j] * w2[j * 12 + t];
        s2 *= 1e-12f;                                   // affine_res element
        ssh[t] = fabsf(s2);
        float e = ((t & 3) == (t >> 2)) ? 1.f : 0.f;    // eye(3,4) diag 0,5,10
        affine_out[t] = s2 + e;
    }
    __syncthreads();
    if (t == 0) {
        float sa = 0.f;
        #pragma unroll
        for (int i = 0; i < 12; ++i) sa += ssh[i];
        *mean_out = sa * (1.f / 12.f);
    }
}

__global__ __launch_bounds__(256) void transfer_sh_kernel(
    const float* __restrict__ positions,
    const int*   __restrict__ indexes,
    const float* __restrict__ cam_pos,
    const float* __restrict__ base_sh,
    const float* __restrict__ higher_sh,
    const float* __restrict__ affine,   // 12 f32 (row-major 3x4), from ws
    float* __restrict__ out,            // (N,3)
    int n)
{
    int i = blockIdx.x * blockDim.x + threadIdx.x;
    if (i >= n) return;

    // direction
    float px = positions[3 * i + 0] - cam_pos[0];
    float py = positions[3 * i + 1] - cam_pos[1];
    float pz = positions[3 * i + 2] - cam_pos[2];
    float rn = rsqrtf(px * px + py * py + pz * pz);
    float x = px * rn, y = py * rn, z = pz * rn;

    float xx = x * x, yy = y * y, zz = z * z;
    float xy = x * y, yz = y * z, xz = x * z;

    // deg-3 SH basis (b[0] folded into base term below)
    float b[16];
    b[1]  = -0.4886025119029199f * y;
    b[2]  =  0.4886025119029199f * z;
    b[3]  = -0.4886025119029199f * x;
    b[4]  =  1.0925484305920792f * xy;
    b[5]  = -1.0925484305920792f * yz;
    b[6]  =  0.31539156525252005f * (2.f * zz - xx - yy);
    b[7]  = -1.0925484305920792f * xz;
    b[8]  =  0.5462742152960396f * (xx - yy);
    b[9]  = -0.5900435899266435f * y * (3.f * xx - yy);
    b[10] =  2.890611442640554f  * xy * z;
    b[11] = -0.4570457994644658f * y * (4.f * zz - xx - yy);
    b[12] =  0.3731763325901154f * z * (2.f * zz - 3.f * xx - 3.f * yy);
    b[13] = -0.4570457994644658f * x * (4.f * zz - xx - yy);
    b[14] =  1.445305721320277f  * z * (xx - yy);
    b[15] = -0.5900435899266435f * x * (xx - yy);

    unsigned idx = (unsigned)indexes[i];

    // base_sh gather: 3 scalar loads
    float a0 = base_sh[3 * idx + 0];
    float a1 = base_sh[3 * idx + 1];
    float a2 = base_sh[3 * idx + 2];
    const float C0 = 0.28209479177387814f;
    float c0 = a0 * C0 + 0.5f;
    float c1 = a1 * C0 + 0.5f;
    float c2 = a2 * C0 + 0.5f;

    // higher_sh gather: 45 floats at float-offset fo = 45*idx (only 4B-aligned).
    // Read the enclosing 16B-aligned 192B window as 12 float4 (window always
    // covers the row: misalign m = fo&3 <= 3 floats, m+45 <= 48), then a 4-way
    // switch on m does the dot products with compile-time shifted indices.
    unsigned fo = 45u * idx;
    const float4* W = (const float4*)(higher_sh + (fo & ~3u));
    float4 v[12];
    #pragma unroll
    for (int q = 0; q < 12; ++q) v[q] = W[q];
    float Wf[48];
    #pragma unroll
    for (int q = 0; q < 12; ++q) {
        Wf[4 * q + 0] = v[q].x; Wf[4 * q + 1] = v[q].y;
        Wf[4 * q + 2] = v[q].z; Wf[4 * q + 3] = v[q].w;
    }

#define ACC(M)                                      \
    {                                               \
        _Pragma("unroll")                           \
        for (int k = 0; k < 15; ++k) {              \
            c0 += Wf[(M) + k]      * b[k + 1];      \
            c1 += Wf[(M) + 15 + k] * b[k + 1];      \
            c2 += Wf[(M) + 30 + k] * b[k + 1];      \
        }                                           \
    }
    switch (fo & 3u) {
        case 0: ACC(0) break;
        case 1: ACC(1) break;
        case 2: ACC(2) break;
        default: ACC(3) break;
    }
#undef ACC

    // affine (broadcast, L1-resident) + clamp + store
    #pragma unroll
    for (int r = 0; r < 3; ++r) {
        float vv = c0 * affine[4 * r + 0] + c1 * affine[4 * r + 1] +
                   c2 * affine[4 * r + 2] + affine[4 * r + 3];
        vv = fminf(fmaxf(vv, 0.f), 1.f);
        out[3 * i + r] = vv;
    }
}

extern "C" void kernel_launch(void* const* d_in, const int* in_sizes, int n_in,
                              void* d_out, int out_size, void* d_ws, size_t ws_size,
                              hipStream_t stream) {
    const float* positions = (const float*)d_in[0];
    const int*   indexes   = (const int*)d_in[1];
    const float* cam_pos   = (const float*)d_in[2];
    const float* glo       = (const float*)d_in[3];
    const float* base_sh   = (const float*)d_in[4];
    const float* higher_sh = (const float*)d_in[5];
    const float* w1        = (const float*)d_in[6];
    const float* b1        = (const float*)d_in[7];
    const float* ln_w      = (const float*)d_in[8];
    const float* ln_b      = (const float*)d_in[9];
    const float* w2        = (const float*)d_in[10];
    const float* b2        = (const float*)d_in[11];

    float* out    = (float*)d_out;
    float* affine = (float*)d_ws;            // 12 floats scratch

    int n = in_sizes[0] / 3;                 // number of points
    float* mean_out = out + (out_size - 1);  // scalar output at tail

    mlp_prologue_kernel<<<1, 64, 0, stream>>>(glo, w1, b1, ln_w, ln_b, w2, b2,
                                              affine, mean_out);

    int block = 256;
    int grid = (n + block - 1) / block;
    transfer_sh_kernel<<<grid, block, 0, stream>>>(positions, indexes, cam_pos,
                                                   base_sh, higher_sh, affine,
                                                   out, n);
}